// Round 1
// baseline (1857.242 us; speedup 1.0000x reference)
//
#include <hip/hip_runtime.h>

#define NCLASS 32

// ---------- embedding + MLP: h0 = (emb[g]*x + bias[g]) -> relu(@W1.T+b1) -> @W2.T+b2
__global__ void k_h0(const float* __restrict__ x,
                     const float* __restrict__ emb,
                     const float* __restrict__ bias,
                     const float* __restrict__ W1,
                     const float* __restrict__ b1,
                     const float* __restrict__ W2,
                     const float* __restrict__ b2,
                     float* __restrict__ h0,
                     int N, int ngenes) {
    int tid = blockIdx.x * 256 + threadIdx.x;
    int node = tid >> 5;
    int c = tid & 31;
    int nl = threadIdx.x >> 5;              // 0..7 node slot in block
    __shared__ float hb[8][33];
    if (node < N) {
        int g = node % ngenes;
        float h = emb[g * NCLASS + c] * x[node] + bias[g];
        hb[nl][c] = h;
    }
    __syncthreads();
    float a1 = 0.f;
    if (node < N) {
        a1 = b1[c];
        #pragma unroll
        for (int k = 0; k < 32; ++k) a1 = fmaf(hb[nl][k], W1[c * 32 + k], a1);
        a1 = fmaxf(a1, 0.f);
    }
    __syncthreads();
    if (node < N) hb[nl][c] = a1;
    __syncthreads();
    if (node < N) {
        float a2 = b2[c];
        #pragma unroll
        for (int k = 0; k < 32; ++k) a2 = fmaf(hb[nl][k], W2[c * 32 + k], a2);
        h0[node * 32 + c] = a2;
    }
}

// ---------- degree histogram (counts include the +1 self-loop via init)
__global__ void k_fill(int* __restrict__ deg, int N) {
    int i = blockIdx.x * 256 + threadIdx.x;
    if (i < N) deg[i] = 1;
}

__global__ void k_hist(const int* __restrict__ col, int E, int* __restrict__ deg) {
    int stride = gridDim.x * blockDim.x;
    for (int e = blockIdx.x * blockDim.x + threadIdx.x; e < E; e += stride)
        atomicAdd(&deg[col[e]], 1);
}

__global__ void k_dinv(const int* __restrict__ deg, float* __restrict__ dinv, int N) {
    int i = blockIdx.x * 256 + threadIdx.x;
    if (i < N) dinv[i] = rsqrtf((float)deg[i]);   // deg >= 1 always (self-loop)
}

// ---------- hierarchical exclusive prefix scan of deg -> offsets
__global__ void k_scan_block(const int* __restrict__ deg, int* __restrict__ exc,
                             int* __restrict__ bsum, int N) {
    __shared__ int s[256];
    int t = threadIdx.x;
    int i = blockIdx.x * 256 + t;
    int v = (i < N) ? deg[i] : 0;
    s[t] = v;
    __syncthreads();
    for (int off = 1; off < 256; off <<= 1) {
        int tmp = (t >= off) ? s[t - off] : 0;
        __syncthreads();
        s[t] += tmp;
        __syncthreads();
    }
    if (i < N) exc[i] = s[t] - v;          // exclusive within block
    if (t == 255) bsum[blockIdx.x] = s[255];
}

__global__ void k_scan_top(int* __restrict__ bsum, int nb) {
    __shared__ int s[1024];
    int t = threadIdx.x;
    int v = (t < nb) ? bsum[t] : 0;
    s[t] = v;
    __syncthreads();
    for (int off = 1; off < 1024; off <<= 1) {
        int tmp = (t >= off) ? s[t - off] : 0;
        __syncthreads();
        s[t] += tmp;
        __syncthreads();
    }
    if (t < nb) bsum[t] = s[t] - v;        // exclusive block offsets
}

__global__ void k_scan_add(const int* __restrict__ exc, const int* __restrict__ bsum,
                           int* __restrict__ offsets, int* __restrict__ cursor,
                           int N, int total) {
    int i = blockIdx.x * 256 + threadIdx.x;
    if (i < N) {
        int o = exc[i] + bsum[blockIdx.x];
        offsets[i] = o;
        cursor[i] = o;
    }
    if (i == 0) offsets[N] = total;
}

// ---------- scatter edges (+self-loops) into CSR-by-destination
__global__ void k_scatter(const int* __restrict__ ei, int E, int N,
                          const float* __restrict__ dinv, int* __restrict__ cursor,
                          int* __restrict__ srcs, float* __restrict__ nrm) {
    int stride = gridDim.x * blockDim.x;
    int total = E + N;
    for (int e = blockIdx.x * blockDim.x + threadIdx.x; e < total; e += stride) {
        int r, cl;
        if (e < E) { r = ei[e]; cl = ei[E + e]; }
        else       { r = e - E; cl = r; }
        int p = atomicAdd(&cursor[cl], 1);
        srcs[p] = r;
        nrm[p] = dinv[r] * dinv[cl];
    }
}

// ---------- one APPNP step: hout = 0.9 * (A_norm @ hin) + 0.1 * h0
__global__ __launch_bounds__(256) void k_prop(const float* __restrict__ hin,
                                              const float* __restrict__ h0,
                                              float* __restrict__ hout,
                                              const int* __restrict__ offsets,
                                              const int* __restrict__ srcs,
                                              const float* __restrict__ nrm,
                                              int N) {
    int tid = blockIdx.x * 256 + threadIdx.x;
    int node = tid >> 5;                   // 32 lanes per node, lane = channel
    int c = tid & 31;
    if (node >= N) return;
    int start = offsets[node];
    int end = offsets[node + 1];
    float acc = 0.f;
    for (int e = start; e < end; ++e) {
        int s = srcs[e];                   // broadcast within half-wave
        float w = nrm[e];
        acc = fmaf(w, hin[s * 32 + c], acc);   // coalesced 128B line per edge
    }
    hout[node * 32 + c] = 0.9f * acc + 0.1f * h0[node * 32 + c];
}

// ---------- output zero + mean pool per graph
__global__ void k_zero(float* __restrict__ out, int n) {
    int i = blockIdx.x * 256 + threadIdx.x;
    if (i < n) out[i] = 0.f;
}

__global__ void k_pool(const float* __restrict__ h, float* __restrict__ out, int ngenes) {
    const int cpg = 25;                    // chunks per graph
    int nper = ngenes / cpg;               // 800 nodes per chunk
    int b = blockIdx.x / cpg;
    int chunk = blockIdx.x % cpg;
    int t = threadIdx.x;
    int c = t & 31, grp = t >> 5;
    const float* base = h + ((size_t)b * ngenes + (size_t)chunk * nper) * 32;
    float acc = 0.f;
    for (int i = grp; i < nper; i += 8) acc += base[i * 32 + c];
    __shared__ float s[256];
    s[t] = acc;
    __syncthreads();
    if (t < 128) s[t] += s[t + 128];
    __syncthreads();
    if (t < 64) s[t] += s[t + 64];
    __syncthreads();
    if (t < 32) atomicAdd(&out[b * 32 + c], (s[t] + s[t + 32]) * (1.0f / (float)ngenes));
}

extern "C" void kernel_launch(void* const* d_in, const int* in_sizes, int n_in,
                              void* d_out, int out_size, void* d_ws, size_t ws_size,
                              hipStream_t stream) {
    const float* x    = (const float*)d_in[0];
    const int*   ei   = (const int*)d_in[1];   // [2,E] flat: row at [0,E), col at [E,2E)
    const float* emb  = (const float*)d_in[3];
    const float* bias = (const float*)d_in[4];
    const float* W1   = (const float*)d_in[5];
    const float* b1   = (const float*)d_in[6];
    const float* W2   = (const float*)d_in[7];
    const float* b2   = (const float*)d_in[8];
    float* out = (float*)d_out;

    int N = in_sizes[0];
    int E = in_sizes[1] / 2;
    int ngenes = in_sizes[4];
    int batch = N / ngenes;
    int total = E + N;

    char* p = (char*)d_ws;
    auto carve = [&](size_t bytes) {
        void* r = (void*)p;
        p += (bytes + 255) & ~(size_t)255;
        return r;
    };
    float* h0      = (float*)carve((size_t)N * 32 * 4);
    float* hA      = (float*)carve((size_t)N * 32 * 4);
    float* hB      = (float*)carve((size_t)N * 32 * 4);
    int*   deg     = (int*)carve((size_t)N * 4);
    float* dinv    = (float*)carve((size_t)N * 4);
    int*   exc     = (int*)carve((size_t)N * 4);
    int*   offsets = (int*)carve((size_t)(N + 1) * 4);
    int*   cursor  = (int*)carve((size_t)N * 4);
    int*   bsum    = (int*)carve(4096);
    int*   srcs    = (int*)carve((size_t)total * 4);
    float* nrm     = (float*)carve((size_t)total * 4);

    int nbN = (N + 255) / 256;

    hipLaunchKernelGGL(k_h0, dim3((N * 32 + 255) / 256), dim3(256), 0, stream,
                       x, emb, bias, W1, b1, W2, b2, h0, N, ngenes);
    hipLaunchKernelGGL(k_fill, dim3(nbN), dim3(256), 0, stream, deg, N);
    hipLaunchKernelGGL(k_hist, dim3(2048), dim3(256), 0, stream, ei + E, E, deg);
    hipLaunchKernelGGL(k_dinv, dim3(nbN), dim3(256), 0, stream, deg, dinv, N);
    hipLaunchKernelGGL(k_scan_block, dim3(nbN), dim3(256), 0, stream, deg, exc, bsum, N);
    hipLaunchKernelGGL(k_scan_top, dim3(1), dim3(1024), 0, stream, bsum, nbN);
    hipLaunchKernelGGL(k_scan_add, dim3(nbN), dim3(256), 0, stream, exc, bsum, offsets, cursor, N, total);
    hipLaunchKernelGGL(k_scatter, dim3(2048), dim3(256), 0, stream, ei, E, N, dinv, cursor, srcs, nrm);

    const float* hin = h0;
    float* bufs[2] = {hA, hB};
    for (int it = 0; it < 10; ++it) {
        float* ho = bufs[it & 1];
        hipLaunchKernelGGL(k_prop, dim3((N * 32 + 255) / 256), dim3(256), 0, stream,
                           hin, h0, ho, offsets, srcs, nrm, N);
        hin = ho;
    }

    hipLaunchKernelGGL(k_zero, dim3((out_size + 255) / 256), dim3(256), 0, stream, out, out_size);
    hipLaunchKernelGGL(k_pool, dim3(batch * 25), dim3(256), 0, stream, hin, out, ngenes);
}

// Round 2
// 951.453 us; speedup vs baseline: 1.9520x; 1.9520x over previous
//
#include <hip/hip_runtime.h>

typedef unsigned int u32;
typedef unsigned short u16;

__device__ inline float bf2f(u16 b) { return __uint_as_float(((u32)b) << 16); }
__device__ inline u16 f2bf(float f) {
    u32 u = __float_as_uint(f);
    return (u16)((u + 0x7fffu + ((u >> 16) & 1u)) >> 16);   // round-to-nearest-even
}
__device__ inline u32 pack2(float a, float b) { return (u32)f2bf(a) | ((u32)f2bf(b) << 16); }

// ---------- embedding + MLP -> h0; writes p0 = dinv*h0 (bf16) and s0 = 0.1*dinv*h0 (bf16)
__global__ void k_h0(const float* __restrict__ x,
                     const float* __restrict__ emb,
                     const float* __restrict__ bias,
                     const float* __restrict__ W1,
                     const float* __restrict__ b1,
                     const float* __restrict__ W2,
                     const float* __restrict__ b2,
                     const float* __restrict__ dinv,
                     u16* __restrict__ p0,
                     u16* __restrict__ s0,
                     int N, int ngenes) {
    int tid = blockIdx.x * 256 + threadIdx.x;
    int node = tid >> 5;
    int c = tid & 31;
    int nl = threadIdx.x >> 5;
    __shared__ float hb[8][33];
    if (node < N) {
        int g = node % ngenes;
        hb[nl][c] = emb[g * 32 + c] * x[node] + bias[g];
    }
    __syncthreads();
    float a1 = 0.f;
    if (node < N) {
        a1 = b1[c];
        #pragma unroll
        for (int k = 0; k < 32; ++k) a1 = fmaf(hb[nl][k], W1[c * 32 + k], a1);
        a1 = fmaxf(a1, 0.f);
    }
    __syncthreads();
    if (node < N) hb[nl][c] = a1;
    __syncthreads();
    if (node < N) {
        float a2 = b2[c];
        #pragma unroll
        for (int k = 0; k < 32; ++k) a2 = fmaf(hb[nl][k], W2[c * 32 + k], a2);
        float dv = dinv[node];
        p0[node * 32 + c] = f2bf(dv * a2);
        s0[node * 32 + c] = f2bf(0.1f * dv * a2);
    }
}

__global__ void k_fill0(int* __restrict__ deg, int N) {
    int i = blockIdx.x * 256 + threadIdx.x;
    if (i < N) deg[i] = 0;
}

__global__ void k_hist(const int* __restrict__ col, int E, int* __restrict__ deg) {
    int stride = gridDim.x * blockDim.x;
    for (int e = blockIdx.x * blockDim.x + threadIdx.x; e < E; e += stride)
        atomicAdd(&deg[col[e]], 1);
}

// dinv = rsqrt(deg+1); a = 0.9*dinv^2; rd = sqrt(deg+1)  (unscale factor for pooling)
__global__ void k_dinv(const int* __restrict__ deg, float* __restrict__ dinv,
                       float* __restrict__ a, float* __restrict__ rd, int N) {
    int i = blockIdx.x * 256 + threadIdx.x;
    if (i < N) {
        float d = (float)(deg[i] + 1);
        float dv = rsqrtf(d);
        dinv[i] = dv;
        a[i] = 0.9f * dv * dv;
        rd[i] = sqrtf(d);
    }
}

// ---------- hierarchical exclusive prefix scan of deg (edge counts only)
__global__ void k_scan_block(const int* __restrict__ deg, int* __restrict__ exc,
                             int* __restrict__ bsum, int N) {
    __shared__ int s[256];
    int t = threadIdx.x;
    int i = blockIdx.x * 256 + t;
    int v = (i < N) ? deg[i] : 0;
    s[t] = v;
    __syncthreads();
    for (int off = 1; off < 256; off <<= 1) {
        int tmp = (t >= off) ? s[t - off] : 0;
        __syncthreads();
        s[t] += tmp;
        __syncthreads();
    }
    if (i < N) exc[i] = s[t] - v;
    if (t == 255) bsum[blockIdx.x] = s[255];
}

__global__ void k_scan_top(int* __restrict__ bsum, int nb) {
    __shared__ int s[1024];
    int t = threadIdx.x;
    int v = (t < nb) ? bsum[t] : 0;
    s[t] = v;
    __syncthreads();
    for (int off = 1; off < 1024; off <<= 1) {
        int tmp = (t >= off) ? s[t - off] : 0;
        __syncthreads();
        s[t] += tmp;
        __syncthreads();
    }
    if (t < nb) bsum[t] = s[t] - v;
}

__global__ void k_scan_add(const int* __restrict__ exc, const int* __restrict__ bsum,
                           int* __restrict__ offsets, int* __restrict__ cursor,
                           int N, int E) {
    int i = blockIdx.x * 256 + threadIdx.x;
    if (i < N) {
        int o = exc[i] + bsum[blockIdx.x];
        offsets[i] = o;
        cursor[i] = o;
    }
    if (i == 0) offsets[N] = E;
}

// ---------- scatter edges into CSR-by-destination (srcs only; no self-loops)
__global__ void k_scatter(const int* __restrict__ ei, int E,
                          int* __restrict__ cursor, int* __restrict__ srcs) {
    int stride = gridDim.x * blockDim.x;
    for (int e = blockIdx.x * blockDim.x + threadIdx.x; e < E; e += stride) {
        int r = ei[e];
        int cl = ei[E + e];
        int p = atomicAdd(&cursor[cl], 1);
        srcs[p] = r;
    }
}

// ---------- one APPNP step on pre-scaled state p (bf16):
// pout[v] = a[v] * (sum_{src in N(v)} pin[src] + pin[v]) + s0[v]
__global__ __launch_bounds__(256) void k_prop(const uint2* __restrict__ pin,
                                              uint2* __restrict__ pout,
                                              const uint2* __restrict__ s0,
                                              const float* __restrict__ a,
                                              const int* __restrict__ offsets,
                                              const int* __restrict__ srcs,
                                              int N) {
    int tid = blockIdx.x * 256 + threadIdx.x;
    int node = tid >> 3;          // 8 lanes per node
    int sub = tid & 7;            // lane handles channels [4*sub, 4*sub+4)
    if (node >= N) return;
    int start = offsets[node];
    int end = offsets[node + 1];
    float a0 = 0.f, a1 = 0.f, a2 = 0.f, a3 = 0.f;
    // self-loop contribution
    {
        uint2 v = pin[node * 8 + sub];
        a0 += bf2f((u16)v.x); a1 += bf2f((u16)(v.x >> 16));
        a2 += bf2f((u16)v.y); a3 += bf2f((u16)(v.y >> 16));
    }
    int e = start;
    for (; e + 1 < end; e += 2) {
        int sA = srcs[e];
        int sB = srcs[e + 1];
        uint2 vA = pin[sA * 8 + sub];
        uint2 vB = pin[sB * 8 + sub];
        a0 += bf2f((u16)vA.x); a1 += bf2f((u16)(vA.x >> 16));
        a2 += bf2f((u16)vA.y); a3 += bf2f((u16)(vA.y >> 16));
        a0 += bf2f((u16)vB.x); a1 += bf2f((u16)(vB.x >> 16));
        a2 += bf2f((u16)vB.y); a3 += bf2f((u16)(vB.y >> 16));
    }
    if (e < end) {
        int sA = srcs[e];
        uint2 vA = pin[sA * 8 + sub];
        a0 += bf2f((u16)vA.x); a1 += bf2f((u16)(vA.x >> 16));
        a2 += bf2f((u16)vA.y); a3 += bf2f((u16)(vA.y >> 16));
    }
    float av = a[node];
    uint2 sv = s0[node * 8 + sub];
    float r0 = fmaf(av, a0, bf2f((u16)sv.x));
    float r1 = fmaf(av, a1, bf2f((u16)(sv.x >> 16)));
    float r2 = fmaf(av, a2, bf2f((u16)sv.y));
    float r3 = fmaf(av, a3, bf2f((u16)(sv.y >> 16)));
    uint2 o;
    o.x = pack2(r0, r1);
    o.y = pack2(r2, r3);
    pout[node * 8 + sub] = o;
}

__global__ void k_zero(float* __restrict__ out, int n) {
    int i = blockIdx.x * 256 + threadIdx.x;
    if (i < n) out[i] = 0.f;
}

// mean pool per graph, unscaling p -> h = p * sqrt(deg+1)
__global__ void k_pool(const u16* __restrict__ p, const float* __restrict__ rd,
                       float* __restrict__ out, int ngenes) {
    const int cpg = 25;
    int nper = ngenes / cpg;
    int b = blockIdx.x / cpg;
    int chunk = blockIdx.x % cpg;
    int t = threadIdx.x;
    int c = t & 31, grp = t >> 5;
    int base = b * ngenes + chunk * nper;
    float acc = 0.f;
    for (int i = grp; i < nper; i += 8) {
        int v = base + i;
        acc += bf2f(p[(size_t)v * 32 + c]) * rd[v];
    }
    __shared__ float s[256];
    s[t] = acc;
    __syncthreads();
    if (t < 128) s[t] += s[t + 128];
    __syncthreads();
    if (t < 64) s[t] += s[t + 64];
    __syncthreads();
    if (t < 32) atomicAdd(&out[b * 32 + c], (s[t] + s[t + 32]) * (1.0f / (float)ngenes));
}

extern "C" void kernel_launch(void* const* d_in, const int* in_sizes, int n_in,
                              void* d_out, int out_size, void* d_ws, size_t ws_size,
                              hipStream_t stream) {
    const float* x    = (const float*)d_in[0];
    const int*   ei   = (const int*)d_in[1];   // [2,E]: row at [0,E), col at [E,2E)
    const float* emb  = (const float*)d_in[3];
    const float* bias = (const float*)d_in[4];
    const float* W1   = (const float*)d_in[5];
    const float* b1   = (const float*)d_in[6];
    const float* W2   = (const float*)d_in[7];
    const float* b2   = (const float*)d_in[8];
    float* out = (float*)d_out;

    int N = in_sizes[0];
    int E = in_sizes[1] / 2;
    int ngenes = in_sizes[4];
    int batch = N / ngenes;

    char* pws = (char*)d_ws;
    auto carve = [&](size_t bytes) {
        void* r = (void*)pws;
        pws += (bytes + 255) & ~(size_t)255;
        return r;
    };
    u16*   pA      = (u16*)carve((size_t)N * 32 * 2);
    u16*   pB      = (u16*)carve((size_t)N * 32 * 2);
    u16*   s0      = (u16*)carve((size_t)N * 32 * 2);
    int*   deg     = (int*)carve((size_t)N * 4);
    float* dinv    = (float*)carve((size_t)N * 4);
    float* afac    = (float*)carve((size_t)N * 4);
    float* rd      = (float*)carve((size_t)N * 4);
    int*   exc     = (int*)carve((size_t)N * 4);
    int*   offsets = (int*)carve((size_t)(N + 1) * 4);
    int*   cursor  = (int*)carve((size_t)N * 4);
    int*   bsum    = (int*)carve(4096);
    int*   srcs    = (int*)carve((size_t)E * 4);

    int nbN = (N + 255) / 256;

    hipLaunchKernelGGL(k_fill0, dim3(nbN), dim3(256), 0, stream, deg, N);
    hipLaunchKernelGGL(k_hist, dim3(2048), dim3(256), 0, stream, ei + E, E, deg);
    hipLaunchKernelGGL(k_dinv, dim3(nbN), dim3(256), 0, stream, deg, dinv, afac, rd, N);
    hipLaunchKernelGGL(k_h0, dim3((N * 32 + 255) / 256), dim3(256), 0, stream,
                       x, emb, bias, W1, b1, W2, b2, dinv, pA, s0, N, ngenes);
    hipLaunchKernelGGL(k_scan_block, dim3(nbN), dim3(256), 0, stream, deg, exc, bsum, N);
    hipLaunchKernelGGL(k_scan_top, dim3(1), dim3(1024), 0, stream, bsum, nbN);
    hipLaunchKernelGGL(k_scan_add, dim3(nbN), dim3(256), 0, stream, exc, bsum, offsets, cursor, N, E);
    hipLaunchKernelGGL(k_scatter, dim3(2048), dim3(256), 0, stream, ei, E, cursor, srcs);

    const u16* hin = pA;
    for (int it = 0; it < 10; ++it) {
        u16* ho = (it & 1) ? pA : pB;
        hipLaunchKernelGGL(k_prop, dim3((N * 8 + 255) / 256), dim3(256), 0, stream,
                           (const uint2*)hin, (uint2*)ho, (const uint2*)s0, afac,
                           offsets, srcs, N);
        hin = ho;
    }

    hipLaunchKernelGGL(k_zero, dim3((out_size + 255) / 256), dim3(256), 0, stream, out, out_size);
    hipLaunchKernelGGL(k_pool, dim3(batch * 25), dim3(256), 0, stream, hin, rd, out, ngenes);
}